// Round 3
// baseline (1998.673 us; speedup 1.0000x reference)
//
#include <hip/hip_runtime.h>

// LSTMBaseline: B=2048, T=512, H=128, 4H=512, FF=64, OUT=2
// fp32 inputs / fp32 outputs (established round 2: sniffer chose fp32 path).
// 256 blocks x 256 threads (4 waves). Each block owns 8 batch rows, runs the
// full T=512 recurrence for both layers. Weights converted once to bf16 MFMA
// fragments held in VGPRs (wave w owns gate columns [128w,128w+128)).
// h carried bf16 (MFMA A operand); c, gates, biases, input proj, head in fp32.

#define TT 512
#define HH 128
#define GG 512
#define FFD 64
#define BB 8
#define HP 136   // padded LDS row stride (ushort)

typedef __attribute__((ext_vector_type(8))) short short8;
typedef __attribute__((ext_vector_type(4))) float f32x4;

__device__ __forceinline__ unsigned short f2b(float f) {
    unsigned int i = __builtin_bit_cast(unsigned int, f);
    i += 0x7FFFu + ((i >> 16) & 1u);   // RNE
    return (unsigned short)(i >> 16);
}
__device__ __forceinline__ float b2f(unsigned short u) {
    return __builtin_bit_cast(float, ((unsigned int)u) << 16);
}
__device__ __forceinline__ float fast_rcp(float x) {
#if __has_builtin(__builtin_amdgcn_rcpf)
    return __builtin_amdgcn_rcpf(x);
#else
    return 1.0f / x;
#endif
}
__device__ __forceinline__ float sigm(float x) {
    return fast_rcp(1.0f + exp2f(-1.4426950408889634f * x));
}
__device__ __forceinline__ float tanh_f(float x) {
    return 1.0f - 2.0f * fast_rcp(1.0f + exp2f(2.8853900817779268f * x));
}
// 8 consecutive fp32 -> bf16 short8 fragment
__device__ __forceinline__ short8 ldfrag(const float* p, unsigned idx) {
    const float4* q = reinterpret_cast<const float4*>(p + idx);
    float4 a = q[0], b = q[1];
    short8 s;
    s[0] = (short)f2b(a.x); s[1] = (short)f2b(a.y);
    s[2] = (short)f2b(a.z); s[3] = (short)f2b(a.w);
    s[4] = (short)f2b(b.x); s[5] = (short)f2b(b.y);
    s[6] = (short)f2b(b.z); s[7] = (short)f2b(b.w);
    return s;
}

__global__ __launch_bounds__(256, 1) void lstm2_fused(
    const float* __restrict__ hr,
    const float* __restrict__ glu,
    const float* __restrict__ wih0,
    const float* __restrict__ whh0,
    const float* __restrict__ bih0,
    const float* __restrict__ bhh0,
    const float* __restrict__ wih1,
    const float* __restrict__ whh1,
    const float* __restrict__ bih1,
    const float* __restrict__ bhh1,
    const float* __restrict__ w1,
    const float* __restrict__ b1,
    const float* __restrict__ w2,
    const float* __restrict__ b2,
    float* __restrict__ out)
{
    __shared__ __align__(16) unsigned short h0s[16][HP];   // bf16; rows 8..15 stay 0
    __shared__ __align__(16) unsigned short h1s[16][HP];
    __shared__ float c0s[BB][HH];
    __shared__ float c1s[BB][HH];
    __shared__ float gates[BB][GG];                        // fp32 gate pre-acts
    __shared__ float hrs[BB][TT];
    __shared__ float glus[BB][TT];
    __shared__ float wih0s[GG][2];
    __shared__ float bias0s[GG];
    __shared__ float bias1s[GG];
    __shared__ float hid[BB][FFD];

    const int tid  = threadIdx.x;
    const int lane = tid & 63;
    const int wv   = tid >> 6;        // 0..3
    const int nrow = lane & 15;       // MFMA m (A) / n (B) index
    const int kg   = lane >> 4;       // MFMA k-group 0..3
    const int b0   = blockIdx.x * BB;

    // ---- init LDS ----
    {
        unsigned short* p0 = &h0s[0][0];
        unsigned short* p1 = &h1s[0][0];
        for (int i = tid; i < 16 * HP; i += 256) { p0[i] = 0; p1[i] = 0; }
        float* pc0 = &c0s[0][0];
        float* pc1 = &c1s[0][0];
        for (int i = tid; i < BB * HH; i += 256) { pc0[i] = 0.f; pc1[i] = 0.f; }
        for (int g = tid; g < GG; g += 256) {
            bias0s[g]   = bih0[g] + bhh0[g];
            bias1s[g]   = bih1[g] + bhh1[g];
            wih0s[g][0] = wih0[2 * g];
            wih0s[g][1] = wih0[2 * g + 1];
        }
        for (int i = tid; i < BB * TT; i += 256) {   // coalesced over t
            int row = i >> 9;
            int t   = i & (TT - 1);
            unsigned gi = (unsigned)(b0 + row) * TT + t;
            hrs[row][t]  = hr[gi];
            glus[row][t] = glu[gi];
        }
    }

    // ---- weight fragments (bf16) in registers ----
    // B-frag 16x16x32: lane(n=lane&15, q=lane>>4) holds B[k=32kt+8q+j][n] = W[gatecol][k]
    const int nb = wv * 128;
    short8 W0f[8][4];   // w_hh0, K=128
    short8 W1f[8][8];   // [w_ih1 ; w_hh1], K=256
#pragma unroll
    for (int nt = 0; nt < 8; nt++) {
        unsigned gc = (unsigned)(nb + nt * 16 + nrow);
#pragma unroll
        for (int kt = 0; kt < 4; kt++) {
            unsigned off = gc * HH + kt * 32 + kg * 8;
            W0f[nt][kt]     = ldfrag(whh0, off);
            W1f[nt][kt]     = ldfrag(wih1, off);
            W1f[nt][kt + 4] = ldfrag(whh1, off);
        }
    }
    __syncthreads();

    // ---- recurrence ----
    for (int t = 0; t < TT; t++) {
        // MM0: gates0 = h0(t-1) @ w_hh0^T
        f32x4 acc[8];
#pragma unroll
        for (int nt = 0; nt < 8; nt++) { f32x4 z = {0.f, 0.f, 0.f, 0.f}; acc[nt] = z; }
#pragma unroll
        for (int kt = 0; kt < 4; kt++) {
            short8 a = *reinterpret_cast<const short8*>(&h0s[nrow][kt * 32 + kg * 8]);
#pragma unroll
            for (int nt = 0; nt < 8; nt++)
                acc[nt] = __builtin_amdgcn_mfma_f32_16x16x32_bf16(a, W0f[nt][kt], acc[nt], 0, 0, 0);
        }
        if (kg < 2) {   // C/D: col=lane&15, row=4*(lane>>4)+r ; batch rows 0..7 valid
#pragma unroll
            for (int nt = 0; nt < 8; nt++) {
                int col = nb + nt * 16 + nrow;
#pragma unroll
                for (int r = 0; r < 4; r++)
                    gates[kg * 4 + r][col] = acc[nt][r];
            }
        }
        __syncthreads();

        // cell0
#pragma unroll
        for (int rep = 0; rep < 4; rep++) {
            int r = (tid >> 7) + rep * 2;
            int j = tid & 127;
            float xh = hrs[r][t];
            float xg = glus[r][t];
            float2 wp0 = *reinterpret_cast<const float2*>(wih0s[j]);
            float2 wp1 = *reinterpret_cast<const float2*>(wih0s[j + 128]);
            float2 wp2 = *reinterpret_cast<const float2*>(wih0s[j + 256]);
            float2 wp3 = *reinterpret_cast<const float2*>(wih0s[j + 384]);
            float pi = gates[r][j]       + bias0s[j]       + xh * wp0.x + xg * wp0.y;
            float pf = gates[r][j + 128] + bias0s[j + 128] + xh * wp1.x + xg * wp1.y;
            float pg = gates[r][j + 256] + bias0s[j + 256] + xh * wp2.x + xg * wp2.y;
            float po = gates[r][j + 384] + bias0s[j + 384] + xh * wp3.x + xg * wp3.y;
            float ig = sigm(pi), fg = sigm(pf), gg = tanh_f(pg), og = sigm(po);
            float c = fg * c0s[r][j] + ig * gg;
            c0s[r][j] = c;
            h0s[r][j] = f2b(og * tanh_f(c));
        }
        __syncthreads();

        // MM1: gates1 = [h0(t), h1(t-1)] @ [w_ih1; w_hh1]^T
#pragma unroll
        for (int nt = 0; nt < 8; nt++) { f32x4 z = {0.f, 0.f, 0.f, 0.f}; acc[nt] = z; }
#pragma unroll
        for (int kt = 0; kt < 8; kt++) {
            short8 a = (kt < 4)
                ? *reinterpret_cast<const short8*>(&h0s[nrow][kt * 32 + kg * 8])
                : *reinterpret_cast<const short8*>(&h1s[nrow][(kt - 4) * 32 + kg * 8]);
#pragma unroll
            for (int nt = 0; nt < 8; nt++)
                acc[nt] = __builtin_amdgcn_mfma_f32_16x16x32_bf16(a, W1f[nt][kt], acc[nt], 0, 0, 0);
        }
        if (kg < 2) {
#pragma unroll
            for (int nt = 0; nt < 8; nt++) {
                int col = nb + nt * 16 + nrow;
#pragma unroll
                for (int r = 0; r < 4; r++)
                    gates[kg * 4 + r][col] = acc[nt][r];
            }
        }
        __syncthreads();

        // cell1
#pragma unroll
        for (int rep = 0; rep < 4; rep++) {
            int r = (tid >> 7) + rep * 2;
            int j = tid & 127;
            float pi = gates[r][j]       + bias1s[j];
            float pf = gates[r][j + 128] + bias1s[j + 128];
            float pg = gates[r][j + 256] + bias1s[j + 256];
            float po = gates[r][j + 384] + bias1s[j + 384];
            float ig = sigm(pi), fg = sigm(pf), gg = tanh_f(pg), og = sigm(po);
            float c = fg * c1s[r][j] + ig * gg;
            c1s[r][j] = c;
            h1s[r][j] = f2b(og * tanh_f(c));
        }
        __syncthreads();
    }

    // ---- head: hidden = relu(h1 @ w1^T + b1); out = hidden @ w2^T + b2 ----
#pragma unroll
    for (int rep = 0; rep < 2; rep++) {
        int r  = (tid >> 6) + rep * 4;   // 0..7
        int ff = tid & 63;
        float a2 = 0.f;
        for (int k = 0; k < HH; k++)
            a2 += b2f(h1s[r][k]) * w1[(unsigned)ff * HH + k];
        hid[r][ff] = fmaxf(a2 + b1[ff], 0.f);
    }
    __syncthreads();
    if (tid < 16) {
        int r = tid >> 1;
        int o = tid & 1;
        float a2 = b2[o];
        for (int k = 0; k < FFD; k++)
            a2 += hid[r][k] * w2[(unsigned)o * FFD + k];
        out[(b0 + r) * 2 + o] = a2;    // fp32 output
    }
}

extern "C" void kernel_launch(void* const* d_in, const int* in_sizes, int n_in,
                              void* d_out, int out_size, void* d_ws, size_t ws_size,
                              hipStream_t stream) {
    const float* hr   = (const float*)d_in[0];
    const float* glu  = (const float*)d_in[1];
    const float* wih0 = (const float*)d_in[2];
    const float* whh0 = (const float*)d_in[3];
    const float* bih0 = (const float*)d_in[4];
    const float* bhh0 = (const float*)d_in[5];
    const float* wih1 = (const float*)d_in[6];
    const float* whh1 = (const float*)d_in[7];
    const float* bih1 = (const float*)d_in[8];
    const float* bhh1 = (const float*)d_in[9];
    const float* w1   = (const float*)d_in[10];
    const float* b1   = (const float*)d_in[11];
    const float* w2   = (const float*)d_in[12];
    const float* b2   = (const float*)d_in[13];
    float* out = (float*)d_out;

    lstm2_fused<<<dim3(2048 / BB), dim3(256), 0, stream>>>(
        hr, glu, wih0, whh0, bih0, bhh0, wih1, whh1, bih1, bhh1,
        w1, b1, w2, b2, out);
}

// Round 4
// 1376.297 us; speedup vs baseline: 1.4522x; 1.4522x over previous
//
#include <hip/hip_runtime.h>

// LSTMBaseline: B=2048, T=512, H=128, 4H=512, FF=64, OUT=2 ; fp32 in/out.
// R3: 256 blocks x 512 threads (8 waves, 2/SIMD). Each block owns 8 batch
// rows, full T=512 recurrence. Wave w owns gate columns [64w, 64w+64):
// weight frags = 48 short8 = 192 VGPRs/lane -> fits 256-VGPR cap, no
// AGPR spill (R2 had 384 -> spill moves dominated). h carried bf16 in LDS,
// c/gates/bias/head fp32.

#define TT 512
#define HH 128
#define GG 512
#define FFD 64
#define BB 8
#define NT 512   // threads per block
#define HP 136   // padded LDS row stride (ushort)

typedef __attribute__((ext_vector_type(8))) short short8;
typedef __attribute__((ext_vector_type(4))) float f32x4;

__device__ __forceinline__ unsigned short f2b(float f) {
    unsigned int i = __builtin_bit_cast(unsigned int, f);
    i += 0x7FFFu + ((i >> 16) & 1u);   // RNE
    return (unsigned short)(i >> 16);
}
__device__ __forceinline__ float b2f(unsigned short u) {
    return __builtin_bit_cast(float, ((unsigned int)u) << 16);
}
__device__ __forceinline__ float fast_rcp(float x) {
#if __has_builtin(__builtin_amdgcn_rcpf)
    return __builtin_amdgcn_rcpf(x);
#else
    return 1.0f / x;
#endif
}
__device__ __forceinline__ float sigm(float x) {
    return fast_rcp(1.0f + exp2f(-1.4426950408889634f * x));
}
__device__ __forceinline__ float tanh_f(float x) {
    return 1.0f - 2.0f * fast_rcp(1.0f + exp2f(2.8853900817779268f * x));
}
// 8 consecutive fp32 -> bf16 short8 fragment
__device__ __forceinline__ short8 ldfrag(const float* p, unsigned idx) {
    const float4* q = reinterpret_cast<const float4*>(p + idx);
    float4 a = q[0], b = q[1];
    short8 s;
    s[0] = (short)f2b(a.x); s[1] = (short)f2b(a.y);
    s[2] = (short)f2b(a.z); s[3] = (short)f2b(a.w);
    s[4] = (short)f2b(b.x); s[5] = (short)f2b(b.y);
    s[6] = (short)f2b(b.z); s[7] = (short)f2b(b.w);
    return s;
}

__global__ __launch_bounds__(NT, 2) void lstm2_fused(
    const float* __restrict__ hr,
    const float* __restrict__ glu,
    const float* __restrict__ wih0,
    const float* __restrict__ whh0,
    const float* __restrict__ bih0,
    const float* __restrict__ bhh0,
    const float* __restrict__ wih1,
    const float* __restrict__ whh1,
    const float* __restrict__ bih1,
    const float* __restrict__ bhh1,
    const float* __restrict__ w1,
    const float* __restrict__ b1,
    const float* __restrict__ w2,
    const float* __restrict__ b2,
    float* __restrict__ out)
{
    __shared__ __align__(16) unsigned short h0s[16][HP];   // bf16; rows 8..15 stay 0
    __shared__ __align__(16) unsigned short h1s[16][HP];
    __shared__ float c0s[BB][HH];
    __shared__ float c1s[BB][HH];
    __shared__ float gates[BB][GG];                        // fp32 gate pre-acts
    __shared__ float hrs[BB][TT];
    __shared__ float glus[BB][TT];
    __shared__ float wih0a[GG];    // split (was float2: 4-way bank conflict)
    __shared__ float wih0b[GG];
    __shared__ float bias0s[GG];
    __shared__ float bias1s[GG];
    __shared__ float hid[BB][FFD];

    const int tid  = threadIdx.x;
    const int lane = tid & 63;
    const int wv   = tid >> 6;        // 0..7
    const int nrow = lane & 15;       // MFMA m (A) / n (B) index
    const int kg   = lane >> 4;       // MFMA k-group 0..3
    const int b0   = blockIdx.x * BB;

    // ---- init LDS ----
    {
        unsigned short* p0 = &h0s[0][0];
        unsigned short* p1 = &h1s[0][0];
        for (int i = tid; i < 16 * HP; i += NT) { p0[i] = 0; p1[i] = 0; }
        float* pc0 = &c0s[0][0];
        float* pc1 = &c1s[0][0];
        for (int i = tid; i < BB * HH; i += NT) { pc0[i] = 0.f; pc1[i] = 0.f; }
        for (int g = tid; g < GG; g += NT) {
            bias0s[g] = bih0[g] + bhh0[g];
            bias1s[g] = bih1[g] + bhh1[g];
            wih0a[g]  = wih0[2 * g];
            wih0b[g]  = wih0[2 * g + 1];
        }
        for (int i = tid; i < BB * TT; i += NT) {   // coalesced over t
            int row = i >> 9;
            int t   = i & (TT - 1);
            unsigned gi = (unsigned)(b0 + row) * TT + t;
            hrs[row][t]  = hr[gi];
            glus[row][t] = glu[gi];
        }
    }

    // ---- weight fragments (bf16) in registers ----
    // B-frag 16x16x32: lane(n=lane&15, q=lane>>4) holds B[k=32kt+8q+j][n] = W[gatecol][k]
    const int nb = wv * 64;           // this wave's gate-column base
    short8 W0f[4][4];   // w_hh0, K=128
    short8 W1f[4][8];   // [w_ih1 ; w_hh1], K=256
#pragma unroll
    for (int nt = 0; nt < 4; nt++) {
        unsigned gc = (unsigned)(nb + nt * 16 + nrow);
#pragma unroll
        for (int kt = 0; kt < 4; kt++) {
            unsigned off = gc * HH + kt * 32 + kg * 8;
            W0f[nt][kt]     = ldfrag(whh0, off);
            W1f[nt][kt]     = ldfrag(wih1, off);
            W1f[nt][kt + 4] = ldfrag(whh1, off);
        }
    }
    __syncthreads();

    // ---- recurrence ----
    for (int t = 0; t < TT; t++) {
        // MM0: gates0 = h0(t-1) @ w_hh0^T
        f32x4 acc[4];
#pragma unroll
        for (int nt = 0; nt < 4; nt++) { f32x4 z = {0.f, 0.f, 0.f, 0.f}; acc[nt] = z; }
#pragma unroll
        for (int kt = 0; kt < 4; kt++) {
            short8 a = *reinterpret_cast<const short8*>(&h0s[nrow][kt * 32 + kg * 8]);
#pragma unroll
            for (int nt = 0; nt < 4; nt++)
                acc[nt] = __builtin_amdgcn_mfma_f32_16x16x32_bf16(a, W0f[nt][kt], acc[nt], 0, 0, 0);
        }
        if (kg < 2) {   // C/D: col=lane&15, row=4*(lane>>4)+r ; batch rows 0..7 valid
#pragma unroll
            for (int nt = 0; nt < 4; nt++) {
                int col = nb + nt * 16 + nrow;
#pragma unroll
                for (int r = 0; r < 4; r++)
                    gates[kg * 4 + r][col] = acc[nt][r];
            }
        }
        __syncthreads();

        // cell0: 8 rows x 128 cols over 512 threads (2 reps)
#pragma unroll
        for (int rep = 0; rep < 2; rep++) {
            int r = (tid >> 7) + rep * 4;    // wave-uniform
            int j = tid & 127;
            float xh = hrs[r][t];
            float xg = glus[r][t];
            float pi = gates[r][j]       + bias0s[j]       + xh * wih0a[j]       + xg * wih0b[j];
            float pf = gates[r][j + 128] + bias0s[j + 128] + xh * wih0a[j + 128] + xg * wih0b[j + 128];
            float pg = gates[r][j + 256] + bias0s[j + 256] + xh * wih0a[j + 256] + xg * wih0b[j + 256];
            float po = gates[r][j + 384] + bias0s[j + 384] + xh * wih0a[j + 384] + xg * wih0b[j + 384];
            float ig = sigm(pi), fg = sigm(pf), gg = tanh_f(pg), og = sigm(po);
            float c = fg * c0s[r][j] + ig * gg;
            c0s[r][j] = c;
            h0s[r][j] = f2b(og * tanh_f(c));
        }
        __syncthreads();

        // MM1: gates1 = [h0(t), h1(t-1)] @ [w_ih1; w_hh1]^T
#pragma unroll
        for (int nt = 0; nt < 4; nt++) { f32x4 z = {0.f, 0.f, 0.f, 0.f}; acc[nt] = z; }
#pragma unroll
        for (int kt = 0; kt < 8; kt++) {
            short8 a = (kt < 4)
                ? *reinterpret_cast<const short8*>(&h0s[nrow][kt * 32 + kg * 8])
                : *reinterpret_cast<const short8*>(&h1s[nrow][(kt - 4) * 32 + kg * 8]);
#pragma unroll
            for (int nt = 0; nt < 4; nt++)
                acc[nt] = __builtin_amdgcn_mfma_f32_16x16x32_bf16(a, W1f[nt][kt], acc[nt], 0, 0, 0);
        }
        if (kg < 2) {
#pragma unroll
            for (int nt = 0; nt < 4; nt++) {
                int col = nb + nt * 16 + nrow;
#pragma unroll
                for (int r = 0; r < 4; r++)
                    gates[kg * 4 + r][col] = acc[nt][r];
            }
        }
        __syncthreads();

        // cell1
#pragma unroll
        for (int rep = 0; rep < 2; rep++) {
            int r = (tid >> 7) + rep * 4;
            int j = tid & 127;
            float pi = gates[r][j]       + bias1s[j];
            float pf = gates[r][j + 128] + bias1s[j + 128];
            float pg = gates[r][j + 256] + bias1s[j + 256];
            float po = gates[r][j + 384] + bias1s[j + 384];
            float ig = sigm(pi), fg = sigm(pf), gg = tanh_f(pg), og = sigm(po);
            float c = fg * c1s[r][j] + ig * gg;
            c1s[r][j] = c;
            h1s[r][j] = f2b(og * tanh_f(c));
        }
        __syncthreads();
    }

    // ---- head: hidden = relu(h1 @ w1^T + b1); out = hidden @ w2^T + b2 ----
    {
        int r  = tid >> 6;      // 0..7
        int ff = tid & 63;
        float a2 = 0.f;
        for (int k = 0; k < HH; k++)
            a2 += b2f(h1s[r][k]) * w1[(unsigned)ff * HH + k];
        hid[r][ff] = fmaxf(a2 + b1[ff], 0.f);
    }
    __syncthreads();
    if (tid < 16) {
        int r = tid >> 1;
        int o = tid & 1;
        float a2 = b2[o];
        for (int k = 0; k < FFD; k++)
            a2 += hid[r][k] * w2[(unsigned)o * FFD + k];
        out[(b0 + r) * 2 + o] = a2;    // fp32 output
    }
}

extern "C" void kernel_launch(void* const* d_in, const int* in_sizes, int n_in,
                              void* d_out, int out_size, void* d_ws, size_t ws_size,
                              hipStream_t stream) {
    const float* hr   = (const float*)d_in[0];
    const float* glu  = (const float*)d_in[1];
    const float* wih0 = (const float*)d_in[2];
    const float* whh0 = (const float*)d_in[3];
    const float* bih0 = (const float*)d_in[4];
    const float* bhh0 = (const float*)d_in[5];
    const float* wih1 = (const float*)d_in[6];
    const float* whh1 = (const float*)d_in[7];
    const float* bih1 = (const float*)d_in[8];
    const float* bhh1 = (const float*)d_in[9];
    const float* w1   = (const float*)d_in[10];
    const float* b1   = (const float*)d_in[11];
    const float* w2   = (const float*)d_in[12];
    const float* b2   = (const float*)d_in[13];
    float* out = (float*)d_out;

    lstm2_fused<<<dim3(2048 / BB), dim3(NT), 0, stream>>>(
        hr, glu, wih0, whh0, bih0, bhh0, wih1, whh1, bih1, bhh1,
        w1, b1, w2, b2, out);
}

// Round 5
// 1319.109 us; speedup vs baseline: 1.5152x; 1.0434x over previous
//
#include <hip/hip_runtime.h>

// LSTMBaseline: B=2048, T=512, H=128, 4H=512, FF=64, OUT=2 ; fp32 in/out.
// R4: software-pipelined layers. 256 blocks x 512 threads (8 waves, 2/SIMD).
// Iteration it: MM phase = { MM0(it), MM1(it-1) } (both read h0(it-1)/h1(it-2)),
// one barrier; cell phase = { cell0(it), cell1(it-1) }, one barrier.
// 2 barriers/step instead of 4. c-state and bias/wih0 in per-thread registers.
// Weights as bf16 MFMA B-frags in regs/AGPRs (wave w owns gate cols [64w,64w+64)).

#define TT 512
#define HH 128
#define GG 512
#define FFD 64
#define BB 8
#define NT 512   // threads per block
#define HP 136   // padded LDS row stride (ushort)

typedef __attribute__((ext_vector_type(8))) short short8;
typedef __attribute__((ext_vector_type(4))) float f32x4;

__device__ __forceinline__ unsigned short f2b(float f) {
    unsigned int i = __builtin_bit_cast(unsigned int, f);
    i += 0x7FFFu + ((i >> 16) & 1u);   // RNE
    return (unsigned short)(i >> 16);
}
__device__ __forceinline__ float b2f(unsigned short u) {
    return __builtin_bit_cast(float, ((unsigned int)u) << 16);
}
__device__ __forceinline__ float fast_rcp(float x) {
#if __has_builtin(__builtin_amdgcn_rcpf)
    return __builtin_amdgcn_rcpf(x);
#else
    return 1.0f / x;
#endif
}
__device__ __forceinline__ float sigm(float x) {
    return fast_rcp(1.0f + exp2f(-1.4426950408889634f * x));
}
__device__ __forceinline__ float tanh_f(float x) {
    return 1.0f - 2.0f * fast_rcp(1.0f + exp2f(2.8853900817779268f * x));
}
// 8 consecutive fp32 -> bf16 short8 fragment
__device__ __forceinline__ short8 ldfrag(const float* p, unsigned idx) {
    const float4* q = reinterpret_cast<const float4*>(p + idx);
    float4 a = q[0], b = q[1];
    short8 s;
    s[0] = (short)f2b(a.x); s[1] = (short)f2b(a.y);
    s[2] = (short)f2b(a.z); s[3] = (short)f2b(a.w);
    s[4] = (short)f2b(b.x); s[5] = (short)f2b(b.y);
    s[6] = (short)f2b(b.z); s[7] = (short)f2b(b.w);
    return s;
}

__global__ __launch_bounds__(NT, 2) void lstm2_fused(
    const float* __restrict__ hr,
    const float* __restrict__ glu,
    const float* __restrict__ wih0,
    const float* __restrict__ whh0,
    const float* __restrict__ bih0,
    const float* __restrict__ bhh0,
    const float* __restrict__ wih1,
    const float* __restrict__ whh1,
    const float* __restrict__ bih1,
    const float* __restrict__ bhh1,
    const float* __restrict__ w1,
    const float* __restrict__ b1,
    const float* __restrict__ w2,
    const float* __restrict__ b2,
    float* __restrict__ out)
{
    __shared__ __align__(16) unsigned short h0s[16][HP];   // bf16; rows 8..15 stay 0
    __shared__ __align__(16) unsigned short h1s[16][HP];
    __shared__ float gates0[BB][GG];                       // layer-0 pre-acts (raw MM)
    __shared__ float gates1[BB][GG];                       // layer-1 pre-acts (raw MM)
    __shared__ float hrs[BB][TT];
    __shared__ float glus[BB][TT];
    __shared__ float hid[BB][FFD];

    const int tid  = threadIdx.x;
    const int lane = tid & 63;
    const int wv   = tid >> 6;        // 0..7
    const int nrow = lane & 15;       // MFMA m (A) / n (B) index
    const int kg   = lane >> 4;       // MFMA k-group 0..3
    const int b0   = blockIdx.x * BB;

    // ---- init LDS ----
    {
        unsigned short* p0 = &h0s[0][0];
        unsigned short* p1 = &h1s[0][0];
        for (int i = tid; i < 16 * HP; i += NT) { p0[i] = 0; p1[i] = 0; }
        for (int i = tid; i < BB * TT; i += NT) {   // coalesced over t
            int row = i >> 9;
            int t   = i & (TT - 1);
            unsigned gi = (unsigned)(b0 + row) * TT + t;
            hrs[row][t]  = hr[gi];
            glus[row][t] = glu[gi];
        }
    }

    // ---- per-thread cell constants (j fixed for the whole kernel) ----
    const int j  = tid & 127;
    const int rb = tid >> 7;          // 0..3 (wave-uniform)
    const float b0i = bih0[j]       + bhh0[j];
    const float b0f = bih0[j + 128] + bhh0[j + 128];
    const float b0g = bih0[j + 256] + bhh0[j + 256];
    const float b0o = bih0[j + 384] + bhh0[j + 384];
    const float b1i = bih1[j]       + bhh1[j];
    const float b1f = bih1[j + 128] + bhh1[j + 128];
    const float b1g = bih1[j + 256] + bhh1[j + 256];
    const float b1o = bih1[j + 384] + bhh1[j + 384];
    const float wai = wih0[2 * j],            wbi = wih0[2 * j + 1];
    const float waf = wih0[2 * (j + 128)],    wbf = wih0[2 * (j + 128) + 1];
    const float wag = wih0[2 * (j + 256)],    wbg = wih0[2 * (j + 256) + 1];
    const float wao = wih0[2 * (j + 384)],    wbo = wih0[2 * (j + 384) + 1];
    float c0r[2] = {0.f, 0.f};
    float c1r[2] = {0.f, 0.f};

    // ---- weight fragments (bf16) in registers/AGPRs ----
    // B-frag 16x16x32: lane(n=lane&15, q=lane>>4) holds B[k=32kt+8q+j][n] = W[gatecol][k]
    const int nb = wv * 64;           // this wave's gate-column base
    short8 W0f[4][4];   // w_hh0, K=128
    short8 W1f[4][8];   // [w_ih1 ; w_hh1], K=256
#pragma unroll
    for (int nt = 0; nt < 4; nt++) {
        unsigned gc = (unsigned)(nb + nt * 16 + nrow);
#pragma unroll
        for (int kt = 0; kt < 4; kt++) {
            unsigned off = gc * HH + kt * 32 + kg * 8;
            W0f[nt][kt]     = ldfrag(whh0, off);
            W1f[nt][kt]     = ldfrag(wih1, off);
            W1f[nt][kt + 4] = ldfrag(whh1, off);
        }
    }
    __syncthreads();

    // ---- pipelined recurrence: it in [0, TT] ----
    for (int it = 0; it <= TT; it++) {
        // ===== MM phase =====
        if (it < TT) {
            // MM0(it): gates0 = h0(it-1) @ w_hh0^T
            f32x4 acc[4];
#pragma unroll
            for (int nt = 0; nt < 4; nt++) { f32x4 z = {0.f, 0.f, 0.f, 0.f}; acc[nt] = z; }
#pragma unroll
            for (int kt = 0; kt < 4; kt++) {
                short8 a = *reinterpret_cast<const short8*>(&h0s[nrow][kt * 32 + kg * 8]);
#pragma unroll
                for (int nt = 0; nt < 4; nt++)
                    acc[nt] = __builtin_amdgcn_mfma_f32_16x16x32_bf16(a, W0f[nt][kt], acc[nt], 0, 0, 0);
            }
            if (kg < 2) {   // C/D: col=lane&15, row=4*(lane>>4)+r ; batch rows 0..7 valid
#pragma unroll
                for (int nt = 0; nt < 4; nt++) {
                    int col = nb + nt * 16 + nrow;
#pragma unroll
                    for (int r = 0; r < 4; r++)
                        gates0[kg * 4 + r][col] = acc[nt][r];
                }
            }
        }
        if (it > 0) {
            // MM1(it-1): gates1 = [h0(it-1), h1(it-2)] @ [w_ih1; w_hh1]^T
            f32x4 acc[4];
#pragma unroll
            for (int nt = 0; nt < 4; nt++) { f32x4 z = {0.f, 0.f, 0.f, 0.f}; acc[nt] = z; }
#pragma unroll
            for (int kt = 0; kt < 8; kt++) {
                short8 a = (kt < 4)
                    ? *reinterpret_cast<const short8*>(&h0s[nrow][kt * 32 + kg * 8])
                    : *reinterpret_cast<const short8*>(&h1s[nrow][(kt - 4) * 32 + kg * 8]);
#pragma unroll
                for (int nt = 0; nt < 4; nt++)
                    acc[nt] = __builtin_amdgcn_mfma_f32_16x16x32_bf16(a, W1f[nt][kt], acc[nt], 0, 0, 0);
            }
            if (kg < 2) {
#pragma unroll
                for (int nt = 0; nt < 4; nt++) {
                    int col = nb + nt * 16 + nrow;
#pragma unroll
                    for (int r = 0; r < 4; r++)
                        gates1[kg * 4 + r][col] = acc[nt][r];
                }
            }
        }
        __syncthreads();

        // ===== cell phase =====
        if (it < TT) {
            // cell0(it): h0(it), c0(it)
#pragma unroll
            for (int rep = 0; rep < 2; rep++) {
                int r = rb + rep * 4;           // wave-uniform
                float xh = hrs[r][it];
                float xg = glus[r][it];
                float pi = gates0[r][j]       + b0i + xh * wai + xg * wbi;
                float pf = gates0[r][j + 128] + b0f + xh * waf + xg * wbf;
                float pg = gates0[r][j + 256] + b0g + xh * wag + xg * wbg;
                float po = gates0[r][j + 384] + b0o + xh * wao + xg * wbo;
                float ig = sigm(pi), fg = sigm(pf), gg = tanh_f(pg), og = sigm(po);
                float c = fg * c0r[rep] + ig * gg;
                c0r[rep] = c;
                h0s[r][j] = f2b(og * tanh_f(c));
            }
        }
        if (it > 0) {
            // cell1(it-1): h1(it-1), c1(it-1)
#pragma unroll
            for (int rep = 0; rep < 2; rep++) {
                int r = rb + rep * 4;
                float pi = gates1[r][j]       + b1i;
                float pf = gates1[r][j + 128] + b1f;
                float pg = gates1[r][j + 256] + b1g;
                float po = gates1[r][j + 384] + b1o;
                float ig = sigm(pi), fg = sigm(pf), gg = tanh_f(pg), og = sigm(po);
                float c = fg * c1r[rep] + ig * gg;
                c1r[rep] = c;
                h1s[r][j] = f2b(og * tanh_f(c));
            }
        }
        __syncthreads();
    }

    // ---- head: hidden = relu(h1 @ w1^T + b1); out = hidden @ w2^T + b2 ----
    {
        int r  = tid >> 6;      // 0..7
        int ff = tid & 63;
        float a2 = 0.f;
        for (int k = 0; k < HH; k++)
            a2 += b2f(h1s[r][k]) * w1[(unsigned)ff * HH + k];
        hid[r][ff] = fmaxf(a2 + b1[ff], 0.f);
    }
    __syncthreads();
    if (tid < 16) {
        int r = tid >> 1;
        int o = tid & 1;
        float a2 = b2[o];
        for (int k = 0; k < FFD; k++)
            a2 += hid[r][k] * w2[(unsigned)o * FFD + k];
        out[(b0 + r) * 2 + o] = a2;    // fp32 output
    }
}

extern "C" void kernel_launch(void* const* d_in, const int* in_sizes, int n_in,
                              void* d_out, int out_size, void* d_ws, size_t ws_size,
                              hipStream_t stream) {
    const float* hr   = (const float*)d_in[0];
    const float* glu  = (const float*)d_in[1];
    const float* wih0 = (const float*)d_in[2];
    const float* whh0 = (const float*)d_in[3];
    const float* bih0 = (const float*)d_in[4];
    const float* bhh0 = (const float*)d_in[5];
    const float* wih1 = (const float*)d_in[6];
    const float* whh1 = (const float*)d_in[7];
    const float* bih1 = (const float*)d_in[8];
    const float* bhh1 = (const float*)d_in[9];
    const float* w1   = (const float*)d_in[10];
    const float* b1   = (const float*)d_in[11];
    const float* w2   = (const float*)d_in[12];
    const float* b2   = (const float*)d_in[13];
    float* out = (float*)d_out;

    lstm2_fused<<<dim3(2048 / BB), dim3(NT), 0, stream>>>(
        hr, glu, wih0, whh0, bih0, bhh0, wih1, whh1, bih1, bhh1,
        w1, b1, w2, b2, out);
}